// Round 13
// baseline (1624.855 us; speedup 1.0000x reference)
//
#include <hip/hip_runtime.h>
#include <stdint.h>

#define T_ 512
#define B_ 64
#define H_ 512
#define L_ 2
#define TBH (T_*B_*H_)   // 16777216
#define BH  (B_*H_)      // 32768
#define NC  8            // time chunks
#define CS  64           // steps per chunk
#define CROWS (CS*B_)    // 4096 rows per chunk
#define CSZ ((size_t)CROWS*H_)       // floats per chunk slot (8 MiB)
#define WPK_OFF  ((size_t)4*CSZ)                     // Whh fp16 pack (1 MiB)
#define WPK_U4L  (64*512)                            // uint4 per layer
#define WIHP_OFF (WPK_OFF + (size_t)2*WPK_U4L*4)     // Wih bf16 pack (1 MiB)
#define Y1_OFF   (WIHP_OFF + (size_t)262144)         // y1 bf16 ring (16 MiB)
#define Y1SZ     ((size_t)CROWS*H_)                  // shorts per y1 slot
#define FLG_OFF  (Y1_OFF + (size_t)2*Y1SZ)           // y1 flags (float offset)

typedef float    f32x4 __attribute__((ext_vector_type(4)));
typedef short    s16x8 __attribute__((ext_vector_type(8)));
typedef short    s16x4 __attribute__((ext_vector_type(4)));
typedef _Float16 h2    __attribute__((ext_vector_type(2)));

static __device__ __forceinline__ short f2bf(float f) {
  uint32_t u = __float_as_uint(f);
  u = (u + 0x7fffu + ((u >> 16) & 1u)) >> 16;  // RNE
  return (short)u;
}

static __device__ __forceinline__ float fdot2(h2 a, h2 b, float c) {
#if __has_builtin(__builtin_amdgcn_fdot2)
  return __builtin_amdgcn_fdot2(a, b, c, false);
#else
  return c + (float)a[0] * (float)b[0] + (float)a[1] * (float)b[1];
#endif
}

template <int IMM>
static __device__ __forceinline__ float swz(float v) {
  return __int_as_float(__builtin_amdgcn_ds_swizzle(__float_as_int(v), IMM));
}

static __device__ __forceinline__ float dpp_xor1(float v) {
  return __int_as_float(__builtin_amdgcn_mov_dpp(__float_as_int(v), 0xB1, 0xF, 0xF, true));
}
static __device__ __forceinline__ float dpp_xor2(float v) {
  return __int_as_float(__builtin_amdgcn_mov_dpp(__float_as_int(v), 0x4E, 0xF, 0xF, true));
}

// Raw workgroup barrier WITHOUT the vmcnt(0) drain __syncthreads carries.
static __device__ __forceinline__ void rawbar() {
  __builtin_amdgcn_sched_barrier(0);
  asm volatile("s_waitcnt lgkmcnt(0)" ::: "memory");
  __builtin_amdgcn_s_barrier();
  __builtin_amdgcn_sched_barrier(0);
}

// Consumer wait (r11-proven): relaxed spin + acquire + syncthreads + fence.
static __device__ __forceinline__ void waitg(uint32_t* c, uint32_t tgt) {
  if (threadIdx.x == 0) {
    while (__hip_atomic_load(c, __ATOMIC_RELAXED, __HIP_MEMORY_SCOPE_AGENT) < tgt)
      __builtin_amdgcn_s_sleep(16);
    (void)__hip_atomic_load(c, __ATOMIC_ACQUIRE, __HIP_MEMORY_SCOPE_AGENT);
  }
  __syncthreads();
  __threadfence();                   // acquire: invalidate stale lines
}

static __device__ __forceinline__ uint32_t pack2(float a, float b) {
  h2 p = { (_Float16)a, (_Float16)b };
  return __builtin_bit_cast(uint32_t, p);
}

static __device__ __forceinline__ h2 bch(uint32_t u) {
  return __builtin_bit_cast(h2, u);
}

// ---------------------------------------------------------------------------
// One-time prepack (68 WGs): Whh->fp16 pack, Wih->bf16, x->bf16 (r12).
// ---------------------------------------------------------------------------
__global__ __launch_bounds__(512, 1)
void prepack(const float* __restrict__ Whh, const float* __restrict__ Wih,
             const float* __restrict__ x, float* __restrict__ ws,
             float* __restrict__ out) {
  const int bid = blockIdx.x, tid = threadIdx.x;
  if (bid < 2) {
    const int l = bid, c = tid & 7, rg = tid >> 3;
    uint4* dst = (uint4*)(ws + WPK_OFF) + (size_t)l * WPK_U4L;
    const float* W = Whh + (size_t)l * H_ * H_;
    #pragma unroll
    for (int k = 0; k < 8; ++k) {
      const float* wrow = W + (size_t)(rg * 8 + k) * H_ + c * 64;
      #pragma unroll
      for (int u = 0; u < 6; ++u) {
        f32x4 w4 = *(const f32x4*)(wrow + u * 8);
        f32x4 w5 = *(const f32x4*)(wrow + u * 8 + 4);
        uint4 pk;
        pk.x = pack2(w4.x, w4.y);
        pk.y = pack2(w4.z, w4.w);
        pk.z = pack2(w5.x, w5.y);
        pk.w = pack2(w5.z, w5.w);
        dst[(k * 6 + u) * 512 + tid] = pk;
      }
      #pragma unroll
      for (int p = 0; p < 2; ++p) {
        f32x4 w4 = *(const f32x4*)(wrow + 48 + p * 8);
        f32x4 w5 = *(const f32x4*)(wrow + 48 + p * 8 + 4);
        uint4 pk;
        pk.x = pack2(w4.x, w4.y);
        pk.y = pack2(w4.z, w4.w);
        pk.z = pack2(w5.x, w5.y);
        pk.w = pack2(w5.z, w5.w);
        dst[(48 + k * 2 + p) * 512 + tid] = pk;
      }
    }
  } else if (bid < 4) {
    const int l = bid - 2;
    const float* src = Wih + (size_t)l * H_ * H_;
    short* dst = (short*)(ws + WIHP_OFF) + (size_t)l * H_ * H_;
    for (int it = 0; it < 64; ++it) {
      int e = (it * 512 + tid) * 8;
      f32x4 a = *(const f32x4*)(src + e);
      f32x4 b = *(const f32x4*)(src + e + 4);
      s16x8 p = { f2bf(a.x), f2bf(a.y), f2bf(a.z), f2bf(a.w),
                  f2bf(b.x), f2bf(b.y), f2bf(b.z), f2bf(b.w) };
      *(s16x8*)(dst + e) = p;
    }
  } else {
    const int w = bid - 4;                 // 0..63: 8 WGs per chunk
    const int cc = w >> 3, sub = w & 7;
    const float* src = x + (size_t)cc * CSZ + (size_t)sub * (CSZ / 8);
    short* dst = (short*)(out + (size_t)cc * CSZ) + (size_t)sub * (CSZ / 8);
    for (int it = 0; it < 64; ++it) {
      int e = (it * 512 + tid) * 8;
      f32x4 a = *(const f32x4*)(src + e);
      f32x4 b = *(const f32x4*)(src + e + 4);
      s16x8 p = { f2bf(a.x), f2bf(a.y), f2bf(a.z), f2bf(a.w),
                  f2bf(b.x), f2bf(b.y), f2bf(b.z), f2bf(b.w) };
      *(s16x8*)(dst + e) = p;
    }
  }
}

// ---------------------------------------------------------------------------
// GEMM role, bf16 inputs (r12, unchanged).
// ---------------------------------------------------------------------------
__device__ void gemm_role(char* smem, int rb,
                          const short* __restrict__ In,
                          const short* __restrict__ W,
                          const float* __restrict__ bi,
                          const float* __restrict__ bh,
                          float* __restrict__ Out) {
  constexpr int LDT = 40;
  short* As = (short*)smem;                    // 256 x LDT
  short* Bs = (short*)(smem + 256 * LDT * 2);  // 128 x LDT

  const int tid  = threadIdx.x;
  const int m0   = (rb >> 2) * 256;
  const int n0   = (rb & 3) * 128;
  const int wave = tid >> 6, lane = tid & 63;
  const int wm   = (wave >> 1) * 64;
  const int wn   = (wave & 1) * 64;
  const int quad = lane >> 4, tq = lane & 15;

  f32x4 acc[4][4] = {};

  for (int k0 = 0; k0 < 512; k0 += 32) {
    #pragma unroll
    for (int v = 0; v < 2; ++v) {            // A: 256 rows x 32 cols bf16
      int idx = v * 512 + tid;
      int r = idx >> 2, cc = (idx & 3) * 8;
      s16x8 a = *(const s16x8*)(In + (size_t)(m0 + r) * 512 + k0 + cc);
      *(s16x8*)(&As[r * LDT + cc]) = a;
    }
    {                                        // B: 128 rows x 32 cols bf16
      int r = tid >> 2, cc = (tid & 3) * 8;
      s16x8 b = *(const s16x8*)(W + (size_t)(n0 + r) * 512 + k0 + cc);
      *(s16x8*)(&Bs[r * LDT + cc]) = b;
    }
    __syncthreads();

    s16x8 af[4], bfr[4];
    #pragma unroll
    for (int mf = 0; mf < 4; ++mf)
      af[mf] = *(const s16x8*)(&As[(wm + mf * 16 + tq) * LDT + quad * 8]);
    #pragma unroll
    for (int nf = 0; nf < 4; ++nf)
      bfr[nf] = *(const s16x8*)(&Bs[(wn + nf * 16 + tq) * LDT + quad * 8]);
    #pragma unroll
    for (int mf = 0; mf < 4; ++mf)
      #pragma unroll
      for (int nf = 0; nf < 4; ++nf)
        acc[mf][nf] = __builtin_amdgcn_mfma_f32_16x16x32_bf16(
            af[mf], bfr[nf], acc[mf][nf], 0, 0, 0);
    __syncthreads();
  }

  #pragma unroll
  for (int nf = 0; nf < 4; ++nf) {
    int col = n0 + wn + nf * 16 + tq;
    float bv = bi[col] + bh[col];
    #pragma unroll
    for (int mf = 0; mf < 4; ++mf) {
      #pragma unroll
      for (int r = 0; r < 4; ++r) {
        int row = m0 + wm + mf * 16 + quad * 4 + r;
        Out[(size_t)row * 512 + col] = acc[mf][nf][r] + bv;
      }
    }
  }
}

// ---------------------------------------------------------------------------
// Recurrence role (r12 body). BF16Y=true (R1): y1 written as bf16; at local
// steps 15/31/47/63 the per-step barrier is a FULL __syncthreads (vmcnt
// drain) + __threadfence + release-add on yflag[ls>>4] -- publishing the
// quarter-chunk to G2 running in the SAME stage. Flags are per-chunk
// (r10 lesson: no epoch conflation). BF16Y=false (R2): unchanged.
// ---------------------------------------------------------------------------
template <bool BF16Y>
__device__ void recur_role(char* smem, int b, int chunk,
                           float* __restrict__ xw_y,
                           short* __restrict__ yb,
                           uint32_t* __restrict__ yflag,
                           const float* __restrict__ h0l,
                           const uint4* __restrict__ wpk,
                           float* __restrict__ hstate) {
  const int tid = threadIdx.x;
  const int c   = tid & 7;

  uint4*    wlds = (uint4*)smem;                     // 16*512 entries, 128 KiB
  _Float16* hbuf = (_Float16*)(smem + 131072);       // [2][8*72]

  const uint4* wp = wpk + tid;
  h2 wreg[8][24];
  #pragma unroll
  for (int k = 0; k < 8; ++k)
    #pragma unroll
    for (int u = 0; u < 6; ++u) {
      uint4 v = wp[(k * 6 + u) * 512];
      wreg[k][u * 4 + 0] = bch(v.x);
      wreg[k][u * 4 + 1] = bch(v.y);
      wreg[k][u * 4 + 2] = bch(v.z);
      wreg[k][u * 4 + 3] = bch(v.w);
    }
  #pragma unroll
  for (int j = 0; j < 16; ++j)
    wlds[j * 512 + tid] = wp[(48 + j) * 512];

  float hini = (chunk == 0) ? h0l[b * 512 + tid] : hstate[b * 512 + tid];
  hbuf[(tid >> 6) * 72 + (tid & 63)] = (_Float16)hini;   // parity 0 (ls=0 even)
  __syncthreads();

#define UBLK(HV, W0)                                                        \
  { h2 p0 = bch((HV).x), p1 = bch((HV).y), p2 = bch((HV).z), p3 = bch((HV).w); \
    _Pragma("unroll")                                                       \
    for (int k = 0; k < 8; ++k) {                                           \
      acc[k] = fdot2(wreg[k][(W0) + 0], p0, acc[k]);                        \
      acc[k] = fdot2(wreg[k][(W0) + 1], p1, acc[k]);                        \
      acc[k] = fdot2(wreg[k][(W0) + 2], p2, acc[k]);                        \
      acc[k] = fdot2(wreg[k][(W0) + 3], p3, acc[k]);                        \
    } }

#define WLDX(g)                                                             \
  { wt0 = wlds[(4 * (g) + 0) * 512 + tid];                                  \
    wt1 = wlds[(4 * (g) + 1) * 512 + tid];                                  \
    wt2 = wlds[(4 * (g) + 2) * 512 + tid];                                  \
    wt3 = wlds[(4 * (g) + 3) * 512 + tid]; }

#define CONSX(K0)                                                           \
  { h2 q0 = bch(q4.x), q1 = bch(q4.y), q2 = bch(q4.z), q3 = bch(q4.w);      \
    h2 r0 = bch(r4.x), r1 = bch(r4.y), r2 = bch(r4.z), r3 = bch(r4.w);      \
    float a = acc[(K0)];                                                    \
    a = fdot2(bch(wt0.x), q0, a); a = fdot2(bch(wt0.y), q1, a);             \
    a = fdot2(bch(wt0.z), q2, a); a = fdot2(bch(wt0.w), q3, a);             \
    a = fdot2(bch(wt1.x), r0, a); a = fdot2(bch(wt1.y), r1, a);             \
    a = fdot2(bch(wt1.z), r2, a); a = fdot2(bch(wt1.w), r3, a);             \
    acc[(K0)] = a;                                                          \
    a = acc[(K0) + 1];                                                      \
    a = fdot2(bch(wt2.x), q0, a); a = fdot2(bch(wt2.y), q1, a);             \
    a = fdot2(bch(wt2.z), q2, a); a = fdot2(bch(wt2.w), q3, a);             \
    a = fdot2(bch(wt3.x), r0, a); a = fdot2(bch(wt3.y), r1, a);             \
    a = fdot2(bch(wt3.z), r2, a); a = fdot2(bch(wt3.w), r3, a);             \
    acc[(K0) + 1] = a; }

  const float* xwp = xw_y + (size_t)b * 512 + tid;
  float xwv = xwp[0];
  float hlast = 0.f;
  for (int ls = 0; ls < CS; ++ls) {
    const int cur = ls & 1, nxt = cur ^ 1;
    int tn = (ls + 1 < CS) ? ls + 1 : ls;
    float xwn = xwp[(size_t)tn * BH];   // prefetch rides across rawbar

    const _Float16* hc = &hbuf[cur * 8 * 72 + c * 72];
#define HLD(i) (*(const uint4*)(hc + (i) * 8))

    float acc[8] = {0, 0, 0, 0, 0, 0, 0, 0};

    uint4 ha = HLD(0), hbv = HLD(1), hx = HLD(2);
    uint4 q4 = HLD(6), r4 = HLD(7);
    uint4 wt0, wt1, wt2, wt3;

    WLDX(0);                         // k=0,1 in flight
    UBLK(ha, 0);   ha  = HLD(3);     // cols  0..7
    CONSX(0);      WLDX(1);          // consume k=0,1; issue k=2,3
    UBLK(hbv, 4);  hbv = HLD(4);     // cols  8..15
    CONSX(2);      WLDX(2);          // consume k=2,3; issue k=4,5
    UBLK(hx, 8);   hx  = HLD(5);     // cols 16..23
    CONSX(4);      WLDX(3);          // consume k=4,5; issue k=6,7
    UBLK(ha, 12);                    // cols 24..31
    CONSX(6);                        // consume k=6,7
    UBLK(hbv, 16);                   // cols 32..39
    UBLK(hx, 20);                    // cols 40..47

    // butterfly: xor1/xor2 on DPP (VALU), xor4 via ds_swizzle
    float r1v[4];
    #pragma unroll
    for (int p = 0; p < 4; ++p) {
      float send = (c & 1) ? acc[2 * p] : acc[2 * p + 1];
      float recv = dpp_xor1(send);
      float keep = (c & 1) ? acc[2 * p + 1] : acc[2 * p];
      r1v[p] = keep + recv;
    }
    float r2v[2];
    #pragma unroll
    for (int p = 0; p < 2; ++p) {
      float send = (c & 2) ? r1v[2 * p] : r1v[2 * p + 1];
      float recv = dpp_xor2(send);
      float keep = (c & 2) ? r1v[2 * p + 1] : r1v[2 * p];
      r2v[p] = keep + recv;
    }
    {
      float send = (c & 4) ? r2v[0] : r2v[1];
      float recv = swz<0x101F>(send);
      float keep = (c & 4) ? r2v[1] : r2v[0];
      float dot  = keep + recv;              // full dot for row == tid

      float pre = dot + xwv;
      float e   = __expf(2.f * pre);         // tanh = 1 - 2/(e^{2x}+1)
      float hni = 1.f - 2.f / (e + 1.f);
      hbuf[nxt * 8 * 72 + (tid >> 6) * 72 + (tid & 63)] = (_Float16)hni;
      if constexpr (BF16Y)
        yb[(size_t)ls * BH + b * 512 + tid] = f2bf(hni);
      else
        xw_y[(size_t)ls * BH + b * 512 + tid] = hni;
      hlast = hni;
    }
    if (BF16Y && ((ls & 15) == 15)) {
      // quarter-chunk publish: full drain + release + flag arrive
      __syncthreads();               // drains vmcnt -> y1 stores complete
      __threadfence();               // release: L2 writeback
      if (tid == 0)
        __hip_atomic_fetch_add(&yflag[ls >> 4], 1u,
                               __ATOMIC_RELEASE, __HIP_MEMORY_SCOPE_AGENT);
    } else {
      rawbar();                      // lgkm-only barrier; y-store not drained
    }
    xwv = xwn;
#undef HLD
  }
  hstate[b * 512 + tid] = hlast;   // final chunk leaves h_n in place
#undef UBLK
#undef WLDX
#undef CONSX
}

// ---------------------------------------------------------------------------
// Pipeline stage s (r13: G2 moved INTO R1's stage via intra-launch flags):
//   blocks   0..63  R1: recur L0, chunk s      publishes y1 quarter-flags
//   blocks  64..127 R2: recur L1, chunk s-1    reads out[s-1] (G2, stage s-1)
//   blocks 128..191 G1: x(bf16) @ W1p -> f32 xw1 ring          [cc = s+1]
//   blocks 192..255 G2: y1(bf16 ring) @ W2p -> f32 out[cc]     [cc = s  ]
//      G2 tile i (steps 4i..4i+3) waits yflag[cc*4 + ((4i+3)>>4)] == 64.
// Launched s = -1..8 (10 stages, was 11). Wait graph acyclic (R1 never
// waits intra-stage) => no deadlock even without full co-residency.
// ---------------------------------------------------------------------------
__global__ __launch_bounds__(512, 1)
void stage(int s, const float* __restrict__ h0,
           const float* __restrict__ bih, const float* __restrict__ bhh,
           float* __restrict__ ws, float* __restrict__ out) {
  __shared__ __align__(16) char smem[133376];  // 128K wlds + 2.25K hbuf
  const int role = blockIdx.x >> 6;
  const int rb   = blockIdx.x & 63;
  float* hn = out + (size_t)TBH;
  const uint4* wpk  = (const uint4*)(ws + WPK_OFF);
  const short* wihp = (const short*)(ws + WIHP_OFF);
  short*       y1b  = (short*)(ws + Y1_OFF);
  uint32_t*    yfl  = (uint32_t*)(ws + FLG_OFF);   // [NC][4] quarter flags

  if (role == 0) {                    // R1
    int cc = s;
    if (cc < 0 || cc >= NC) return;
    recur_role<true>(smem, rb, cc, ws + (size_t)(cc & 3) * CSZ,
                     y1b + (size_t)(cc & 3) * Y1SZ, yfl + cc * 4,
                     h0, wpk, hn);
  } else if (role == 1) {             // R2
    int cc = s - 1;
    if (cc < 0 || cc >= NC) return;
    recur_role<false>(smem, rb, cc, out + (size_t)cc * CSZ, nullptr, nullptr,
                      h0 + BH, wpk + WPK_U4L, hn + BH);
  } else if (role == 2) {             // G1
    int cc = s + 1;
    if (cc < 0 || cc >= NC) return;
    gemm_role(smem, rb, (const short*)(out + (size_t)cc * CSZ), wihp,
              bih, bhh, ws + (size_t)(cc & 3) * CSZ);
  } else {                            // G2 (same stage as R1, flag-gated)
    int cc = s;
    if (cc < 0 || cc >= NC) return;
    int tile = rb >> 2;                        // 16 M-tiles, steps 4i..4i+3
    int q = (4 * tile + 3) >> 4;               // quarter-chunk gate
    waitg(&yfl[cc * 4 + q], 64u);
    gemm_role(smem, rb, y1b + (size_t)(cc & 3) * Y1SZ,
              wihp + (size_t)H_ * H_, bih + H_, bhh + H_,
              out + (size_t)cc * CSZ);
  }
}

// ---------------------------------------------------------------------------
extern "C" void kernel_launch(void* const* d_in, const int* in_sizes, int n_in,
                              void* d_out, int out_size, void* d_ws, size_t ws_size,
                              hipStream_t stream) {
  const float* x   = (const float*)d_in[0];
  const float* h0  = (const float*)d_in[1];
  const float* Wih = (const float*)d_in[2];
  const float* Whh = (const float*)d_in[3];
  const float* bih = (const float*)d_in[4];
  const float* bhh = (const float*)d_in[5];
  float* out = (float*)d_out;
  float* ws  = (float*)d_ws;  // 32M ring + 1M Whh + 1M Wih + 16M y1 + flags

  hipMemsetAsync((char*)d_ws + FLG_OFF * sizeof(float), 0, 256, stream);
  prepack<<<68, 512, 0, stream>>>(Whh, Wih, x, ws, out);
  for (int s = -1; s <= NC; ++s)
    stage<<<256, 512, 0, stream>>>(s, h0, bih, bhh, ws, out);
}

// Round 14
// 1117.802 us; speedup vs baseline: 1.4536x; 1.4536x over previous
//
#include <hip/hip_runtime.h>
#include <stdint.h>

#define T_ 512
#define B_ 64
#define H_ 512
#define L_ 2
#define TBH (T_*B_*H_)   // 16777216
#define BH  (B_*H_)      // 32768
#define NC  8            // time chunks (champion config)
#define CS  64           // steps per chunk
#define CROWS (CS*B_)    // 4096 rows per chunk
#define CSZ ((size_t)CROWS*H_)       // floats per chunk slot (8 MiB)
#define WPK_OFF  ((size_t)4*CSZ)                     // Whh fp16 pack (1 MiB)
#define WPK_U4L  (64*512)                            // uint4 per layer
#define WIHP_OFF (WPK_OFF + (size_t)2*WPK_U4L*4)     // Wih bf16 pack (1 MiB)
#define Y1_OFF   (WIHP_OFF + (size_t)262144)         // y1 bf16 ring (16 MiB)
#define Y1SZ     ((size_t)CROWS*H_)                  // shorts per y1 slot

typedef float    f32x4 __attribute__((ext_vector_type(4)));
typedef short    s16x8 __attribute__((ext_vector_type(8)));
typedef short    s16x4 __attribute__((ext_vector_type(4)));
typedef _Float16 h2    __attribute__((ext_vector_type(2)));

static __device__ __forceinline__ short f2bf(float f) {
  uint32_t u = __float_as_uint(f);
  u = (u + 0x7fffu + ((u >> 16) & 1u)) >> 16;  // RNE
  return (short)u;
}

static __device__ __forceinline__ float fdot2(h2 a, h2 b, float c) {
#if __has_builtin(__builtin_amdgcn_fdot2)
  return __builtin_amdgcn_fdot2(a, b, c, false);
#else
  return c + (float)a[0] * (float)b[0] + (float)a[1] * (float)b[1];
#endif
}

template <int IMM>
static __device__ __forceinline__ float swz(float v) {
  return __int_as_float(__builtin_amdgcn_ds_swizzle(__float_as_int(v), IMM));
}

static __device__ __forceinline__ float dpp_xor1(float v) {
  return __int_as_float(__builtin_amdgcn_mov_dpp(__float_as_int(v), 0xB1, 0xF, 0xF, true));
}
static __device__ __forceinline__ float dpp_xor2(float v) {
  return __int_as_float(__builtin_amdgcn_mov_dpp(__float_as_int(v), 0x4E, 0xF, 0xF, true));
}

// Raw workgroup barrier WITHOUT the vmcnt(0) drain __syncthreads carries.
static __device__ __forceinline__ void rawbar() {
  __builtin_amdgcn_sched_barrier(0);
  asm volatile("s_waitcnt lgkmcnt(0)" ::: "memory");
  __builtin_amdgcn_s_barrier();
  __builtin_amdgcn_sched_barrier(0);
}

static __device__ __forceinline__ uint32_t pack2(float a, float b) {
  h2 p = { (_Float16)a, (_Float16)b };
  return __builtin_bit_cast(uint32_t, p);
}

static __device__ __forceinline__ h2 bch(uint32_t u) {
  return __builtin_bit_cast(h2, u);
}

// ---------------------------------------------------------------------------
// One-time prepack (68 WGs):
//   bid 0,1  : Whh -> fp16 consumption-order pack
//   bid 2,3  : Wih -> bf16 row-major (same f2bf bits the GEMM computed/stage)
//   bid 4..67: x   -> bf16, stored in the FIRST HALF of each out[cc] chunk
//              (free scratch: G1 consumes at stage cc-1; G2 overwrites the
//               chunk with f32 xw2 at stage cc+1 -- no lifetime overlap)
// ---------------------------------------------------------------------------
__global__ __launch_bounds__(512, 1)
void prepack(const float* __restrict__ Whh, const float* __restrict__ Wih,
             const float* __restrict__ x, float* __restrict__ ws,
             float* __restrict__ out) {
  const int bid = blockIdx.x, tid = threadIdx.x;
  if (bid < 2) {
    const int l = bid, c = tid & 7, rg = tid >> 3;
    uint4* dst = (uint4*)(ws + WPK_OFF) + (size_t)l * WPK_U4L;
    const float* W = Whh + (size_t)l * H_ * H_;
    #pragma unroll
    for (int k = 0; k < 8; ++k) {
      const float* wrow = W + (size_t)(rg * 8 + k) * H_ + c * 64;
      #pragma unroll
      for (int u = 0; u < 6; ++u) {
        f32x4 w4 = *(const f32x4*)(wrow + u * 8);
        f32x4 w5 = *(const f32x4*)(wrow + u * 8 + 4);
        uint4 pk;
        pk.x = pack2(w4.x, w4.y);
        pk.y = pack2(w4.z, w4.w);
        pk.z = pack2(w5.x, w5.y);
        pk.w = pack2(w5.z, w5.w);
        dst[(k * 6 + u) * 512 + tid] = pk;
      }
      #pragma unroll
      for (int p = 0; p < 2; ++p) {
        f32x4 w4 = *(const f32x4*)(wrow + 48 + p * 8);
        f32x4 w5 = *(const f32x4*)(wrow + 48 + p * 8 + 4);
        uint4 pk;
        pk.x = pack2(w4.x, w4.y);
        pk.y = pack2(w4.z, w4.w);
        pk.z = pack2(w5.x, w5.y);
        pk.w = pack2(w5.z, w5.w);
        dst[(48 + k * 2 + p) * 512 + tid] = pk;
      }
    }
  } else if (bid < 4) {
    const int l = bid - 2;
    const float* src = Wih + (size_t)l * H_ * H_;
    short* dst = (short*)(ws + WIHP_OFF) + (size_t)l * H_ * H_;
    for (int it = 0; it < 64; ++it) {
      int e = (it * 512 + tid) * 8;
      f32x4 a = *(const f32x4*)(src + e);
      f32x4 b = *(const f32x4*)(src + e + 4);
      s16x8 p = { f2bf(a.x), f2bf(a.y), f2bf(a.z), f2bf(a.w),
                  f2bf(b.x), f2bf(b.y), f2bf(b.z), f2bf(b.w) };
      *(s16x8*)(dst + e) = p;
    }
  } else {
    const int w = bid - 4;                 // 0..63: 8 WGs per chunk
    const int cc = w >> 3, sub = w & 7;
    const float* src = x + (size_t)cc * CSZ + (size_t)sub * (CSZ / 8);
    short* dst = (short*)(out + (size_t)cc * CSZ) + (size_t)sub * (CSZ / 8);
    for (int it = 0; it < 64; ++it) {
      int e = (it * 512 + tid) * 8;
      f32x4 a = *(const f32x4*)(src + e);
      f32x4 b = *(const f32x4*)(src + e + 4);
      s16x8 p = { f2bf(a.x), f2bf(a.y), f2bf(a.z), f2bf(a.w),
                  f2bf(b.x), f2bf(b.y), f2bf(b.z), f2bf(b.w) };
      *(s16x8*)(dst + e) = p;
    }
  }
}

// ---------------------------------------------------------------------------
// GEMM role, bf16 inputs: staging per k-iter is 3 x 16B loads + 3 LDS
// writes, zero conversions. Same LDT=40 layout, MFMA schedule, epilogue.
// ---------------------------------------------------------------------------
__device__ void gemm_role(char* smem, int rb,
                          const short* __restrict__ In,
                          const short* __restrict__ W,
                          const float* __restrict__ bi,
                          const float* __restrict__ bh,
                          float* __restrict__ Out) {
  constexpr int LDT = 40;
  short* As = (short*)smem;                    // 256 x LDT
  short* Bs = (short*)(smem + 256 * LDT * 2);  // 128 x LDT

  const int tid  = threadIdx.x;
  const int m0   = (rb >> 2) * 256;
  const int n0   = (rb & 3) * 128;
  const int wave = tid >> 6, lane = tid & 63;
  const int wm   = (wave >> 1) * 64;
  const int wn   = (wave & 1) * 64;
  const int quad = lane >> 4, tq = lane & 15;

  f32x4 acc[4][4] = {};

  for (int k0 = 0; k0 < 512; k0 += 32) {
    #pragma unroll
    for (int v = 0; v < 2; ++v) {            // A: 256 rows x 32 cols bf16
      int idx = v * 512 + tid;
      int r = idx >> 2, cc = (idx & 3) * 8;
      s16x8 a = *(const s16x8*)(In + (size_t)(m0 + r) * 512 + k0 + cc);
      *(s16x8*)(&As[r * LDT + cc]) = a;
    }
    {                                        // B: 128 rows x 32 cols bf16
      int r = tid >> 2, cc = (tid & 3) * 8;
      s16x8 b = *(const s16x8*)(W + (size_t)(n0 + r) * 512 + k0 + cc);
      *(s16x8*)(&Bs[r * LDT + cc]) = b;
    }
    __syncthreads();

    s16x8 af[4], bfr[4];
    #pragma unroll
    for (int mf = 0; mf < 4; ++mf)
      af[mf] = *(const s16x8*)(&As[(wm + mf * 16 + tq) * LDT + quad * 8]);
    #pragma unroll
    for (int nf = 0; nf < 4; ++nf)
      bfr[nf] = *(const s16x8*)(&Bs[(wn + nf * 16 + tq) * LDT + quad * 8]);
    #pragma unroll
    for (int mf = 0; mf < 4; ++mf)
      #pragma unroll
      for (int nf = 0; nf < 4; ++nf)
        acc[mf][nf] = __builtin_amdgcn_mfma_f32_16x16x32_bf16(
            af[mf], bfr[nf], acc[mf][nf], 0, 0, 0);
    __syncthreads();
  }

  #pragma unroll
  for (int nf = 0; nf < 4; ++nf) {
    int col = n0 + wn + nf * 16 + tq;
    float bv = bi[col] + bh[col];
    #pragma unroll
    for (int mf = 0; mf < 4; ++mf) {
      #pragma unroll
      for (int r = 0; r < 4; ++r) {
        int row = m0 + wm + mf * 16 + quad * 4 + r;
        Out[(size_t)row * 512 + col] = acc[mf][nf][r] + bv;
      }
    }
  }
}

// ---------------------------------------------------------------------------
// Recurrence role. BF16Y=true (R1): y written as bf16 (f2bf(hni) -- the
// exact bits G2's staging used to compute) to the y1 ring. BF16Y=false
// (R2): f32 in-place into out.
// ---------------------------------------------------------------------------
template <bool BF16Y>
__device__ void recur_role(char* smem, int b, int chunk,
                           float* __restrict__ xw_y,
                           short* __restrict__ yb,
                           const float* __restrict__ h0l,
                           const uint4* __restrict__ wpk,
                           float* __restrict__ hstate) {
  const int tid = threadIdx.x;
  const int c   = tid & 7;

  uint4*    wlds = (uint4*)smem;                     // 16*512 entries, 128 KiB
  _Float16* hbuf = (_Float16*)(smem + 131072);       // [2][8*72]

  const uint4* wp = wpk + tid;
  h2 wreg[8][24];
  #pragma unroll
  for (int k = 0; k < 8; ++k)
    #pragma unroll
    for (int u = 0; u < 6; ++u) {
      uint4 v = wp[(k * 6 + u) * 512];
      wreg[k][u * 4 + 0] = bch(v.x);
      wreg[k][u * 4 + 1] = bch(v.y);
      wreg[k][u * 4 + 2] = bch(v.z);
      wreg[k][u * 4 + 3] = bch(v.w);
    }
  #pragma unroll
  for (int j = 0; j < 16; ++j)
    wlds[j * 512 + tid] = wp[(48 + j) * 512];

  float hini = (chunk == 0) ? h0l[b * 512 + tid] : hstate[b * 512 + tid];
  hbuf[(tid >> 6) * 72 + (tid & 63)] = (_Float16)hini;   // parity 0 (ls=0 even)
  __syncthreads();

#define UBLK(HV, W0)                                                        \
  { h2 p0 = bch((HV).x), p1 = bch((HV).y), p2 = bch((HV).z), p3 = bch((HV).w); \
    _Pragma("unroll")                                                       \
    for (int k = 0; k < 8; ++k) {                                           \
      acc[k] = fdot2(wreg[k][(W0) + 0], p0, acc[k]);                        \
      acc[k] = fdot2(wreg[k][(W0) + 1], p1, acc[k]);                        \
      acc[k] = fdot2(wreg[k][(W0) + 2], p2, acc[k]);                        \
      acc[k] = fdot2(wreg[k][(W0) + 3], p3, acc[k]);                        \
    } }

#define WLDX(g)                                                             \
  { wt0 = wlds[(4 * (g) + 0) * 512 + tid];                                  \
    wt1 = wlds[(4 * (g) + 1) * 512 + tid];                                  \
    wt2 = wlds[(4 * (g) + 2) * 512 + tid];                                  \
    wt3 = wlds[(4 * (g) + 3) * 512 + tid]; }

#define CONSX(K0)                                                           \
  { h2 q0 = bch(q4.x), q1 = bch(q4.y), q2 = bch(q4.z), q3 = bch(q4.w);      \
    h2 r0 = bch(r4.x), r1 = bch(r4.y), r2 = bch(r4.z), r3 = bch(r4.w);      \
    float a = acc[(K0)];                                                    \
    a = fdot2(bch(wt0.x), q0, a); a = fdot2(bch(wt0.y), q1, a);             \
    a = fdot2(bch(wt0.z), q2, a); a = fdot2(bch(wt0.w), q3, a);             \
    a = fdot2(bch(wt1.x), r0, a); a = fdot2(bch(wt1.y), r1, a);             \
    a = fdot2(bch(wt1.z), r2, a); a = fdot2(bch(wt1.w), r3, a);             \
    acc[(K0)] = a;                                                          \
    a = acc[(K0) + 1];                                                      \
    a = fdot2(bch(wt2.x), q0, a); a = fdot2(bch(wt2.y), q1, a);             \
    a = fdot2(bch(wt2.z), q2, a); a = fdot2(bch(wt2.w), q3, a);             \
    a = fdot2(bch(wt3.x), r0, a); a = fdot2(bch(wt3.y), r1, a);             \
    a = fdot2(bch(wt3.z), r2, a); a = fdot2(bch(wt3.w), r3, a);             \
    acc[(K0) + 1] = a; }

  const float* xwp = xw_y + (size_t)b * 512 + tid;
  float xwv = xwp[0];
  float hlast = 0.f;
  for (int ls = 0; ls < CS; ++ls) {
    const int cur = ls & 1, nxt = cur ^ 1;
    int tn = (ls + 1 < CS) ? ls + 1 : ls;
    float xwn = xwp[(size_t)tn * BH];   // prefetch rides across rawbar

    const _Float16* hc = &hbuf[cur * 8 * 72 + c * 72];
#define HLD(i) (*(const uint4*)(hc + (i) * 8))

    float acc[8] = {0, 0, 0, 0, 0, 0, 0, 0};

    uint4 ha = HLD(0), hbv = HLD(1), hx = HLD(2);
    uint4 q4 = HLD(6), r4 = HLD(7);
    uint4 wt0, wt1, wt2, wt3;

    WLDX(0);                         // k=0,1 in flight
    UBLK(ha, 0);   ha  = HLD(3);     // cols  0..7
    CONSX(0);      WLDX(1);          // consume k=0,1; issue k=2,3
    UBLK(hbv, 4);  hbv = HLD(4);     // cols  8..15
    CONSX(2);      WLDX(2);          // consume k=2,3; issue k=4,5
    UBLK(hx, 8);   hx  = HLD(5);     // cols 16..23
    CONSX(4);      WLDX(3);          // consume k=4,5; issue k=6,7
    UBLK(ha, 12);                    // cols 24..31
    CONSX(6);                        // consume k=6,7
    UBLK(hbv, 16);                   // cols 32..39
    UBLK(hx, 20);                    // cols 40..47

    // butterfly: xor1/xor2 on DPP (VALU), xor4 via ds_swizzle
    float r1v[4];
    #pragma unroll
    for (int p = 0; p < 4; ++p) {
      float send = (c & 1) ? acc[2 * p] : acc[2 * p + 1];
      float recv = dpp_xor1(send);
      float keep = (c & 1) ? acc[2 * p + 1] : acc[2 * p];
      r1v[p] = keep + recv;
    }
    float r2v[2];
    #pragma unroll
    for (int p = 0; p < 2; ++p) {
      float send = (c & 2) ? r1v[2 * p] : r1v[2 * p + 1];
      float recv = dpp_xor2(send);
      float keep = (c & 2) ? r1v[2 * p + 1] : r1v[2 * p];
      r2v[p] = keep + recv;
    }
    {
      float send = (c & 4) ? r2v[0] : r2v[1];
      float recv = swz<0x101F>(send);
      float keep = (c & 4) ? r2v[1] : r2v[0];
      float dot  = keep + recv;              // full dot for row == tid

      float pre = dot + xwv;
      float e   = __expf(2.f * pre);         // tanh = 1 - 2/(e^{2x}+1)
      float hni = 1.f - 2.f / (e + 1.f);
      hbuf[nxt * 8 * 72 + (tid >> 6) * 72 + (tid & 63)] = (_Float16)hni;
      if constexpr (BF16Y)
        yb[(size_t)ls * BH + b * 512 + tid] = f2bf(hni);
      else
        xw_y[(size_t)ls * BH + b * 512 + tid] = hni;
      hlast = hni;
    }
    rawbar();                        // lgkm-only barrier; y-store not drained
    xwv = xwn;
#undef HLD
  }
  hstate[b * 512 + tid] = hlast;   // final chunk leaves h_n in place
#undef UBLK
#undef WLDX
#undef CONSX
}

// ---------------------------------------------------------------------------
// Pipeline stage s (r12 champion structure, bf16 GEMM dataflow):
//   blocks   0..63  R1: recur L0, chunk s    reads f32 xw1 ring; writes bf16 y1
//   blocks  64..127 R2: recur L1, chunk s-2  reads/writes out (f32, in-place)
//   blocks 128..191 G1: x(bf16, in out[cc]) @ W1p -> f32 xw1 ring   [cc=s+1]
//   blocks 192..255 G2: y1(bf16 ring) @ W2p -> f32 xw2 in out[cc]   [cc=s-1]
// Launch-grained 4-role pipeline, depth NC+3 = 11. Settled findings:
// finer-grained R<->G overlap loses (G per-WG tile latency ~50us ~ R chunk;
// r8/r11/r13); VMEM weight streaming loses (r1/r6); this structure's step
// time sits on the measured LDS-pipe floor.
// ---------------------------------------------------------------------------
__global__ __launch_bounds__(512, 1)
void stage(int s, const float* __restrict__ h0,
           const float* __restrict__ bih, const float* __restrict__ bhh,
           float* __restrict__ ws, float* __restrict__ out) {
  __shared__ __align__(16) char smem[133376];  // 128K wlds + 2.25K hbuf
  const int role = blockIdx.x >> 6;
  const int rb   = blockIdx.x & 63;
  float* hn = out + (size_t)TBH;
  const uint4* wpk  = (const uint4*)(ws + WPK_OFF);
  const short* wihp = (const short*)(ws + WIHP_OFF);
  short*       y1b  = (short*)(ws + Y1_OFF);

  if (role == 0) {                    // R1
    int cc = s;
    if (cc < 0 || cc >= NC) return;
    recur_role<true>(smem, rb, cc, ws + (size_t)(cc & 3) * CSZ,
                     y1b + (size_t)(cc & 3) * Y1SZ, h0, wpk, hn);
  } else if (role == 1) {             // R2
    int cc = s - 2;
    if (cc < 0 || cc >= NC) return;
    recur_role<false>(smem, rb, cc, out + (size_t)cc * CSZ, nullptr,
                      h0 + BH, wpk + WPK_U4L, hn + BH);
  } else if (role == 2) {             // G1
    int cc = s + 1;
    if (cc < 0 || cc >= NC) return;
    gemm_role(smem, rb, (const short*)(out + (size_t)cc * CSZ), wihp,
              bih, bhh, ws + (size_t)(cc & 3) * CSZ);
  } else {                            // G2
    int cc = s - 1;
    if (cc < 0 || cc >= NC) return;
    gemm_role(smem, rb, y1b + (size_t)(cc & 3) * Y1SZ,
              wihp + (size_t)H_ * H_, bih + H_, bhh + H_,
              out + (size_t)cc * CSZ);
  }
}

// ---------------------------------------------------------------------------
extern "C" void kernel_launch(void* const* d_in, const int* in_sizes, int n_in,
                              void* d_out, int out_size, void* d_ws, size_t ws_size,
                              hipStream_t stream) {
  const float* x   = (const float*)d_in[0];
  const float* h0  = (const float*)d_in[1];
  const float* Wih = (const float*)d_in[2];
  const float* Whh = (const float*)d_in[3];
  const float* bih = (const float*)d_in[4];
  const float* bhh = (const float*)d_in[5];
  float* out = (float*)d_out;
  float* ws  = (float*)d_ws;  // 32M xw1 ring + 1M Whh pack + 1M Wih bf16 + 16M y1

  prepack<<<68, 512, 0, stream>>>(Whh, Wih, x, ws, out);
  for (int s = -1; s <= NC + 1; ++s)
    stage<<<256, 512, 0, stream>>>(s, h0, bih, bhh, ws, out);
}